// Round 13
// baseline (269.224 us; speedup 1.0000x reference)
//
#include <hip/hip_runtime.h>
#include <hip/hip_bf16.h>
#include <math.h>

#define N_CELLS 16384
#define G_GENES 32
#define IN_DIM  2000
#define HID     1024
#define OUT_DIM 30
#define K_TOT   3024      // IN_DIM + 1024
#define K_PAD   3040      // 95 * 32
#define NT      95
#define GRID_B  128
#define NBINS   (GRID_B * GRID_B)
#define SCELL   (100.0f / (float)GRID_B)
#define CSCALE  0.37796447300922722721f   // 1/sqrt(7)

typedef unsigned short ushort_t;
typedef __attribute__((ext_vector_type(8))) short bf16x8;
typedef __attribute__((ext_vector_type(4))) short bf16x4;
typedef __attribute__((ext_vector_type(4))) float f32x4;

__device__ __forceinline__ ushort_t f2bf(float v) {
  return __builtin_bit_cast(ushort_t, __float2bfloat16(v));
}

// global_load_lds: 16B per lane, LDS dest = wave-uniform base + lane*16
__device__ __forceinline__ void glds16(const void* g, void* l) {
  __builtin_amdgcn_global_load_lds(
      (const __attribute__((address_space(1))) unsigned int*)g,
      (__attribute__((address_space(3))) unsigned int*)l, 16, 0, 0);
}

// ============ fused pre-pass: packb | packw2 | convx | mean_part | bin_count ============
__global__ __launch_bounds__(256) void fused_pre(const float* __restrict__ x,
                                                 const float* __restrict__ W1,
                                                 const float* __restrict__ W2,
                                                 const float* __restrict__ genes,
                                                 const float* __restrict__ coords,
                                                 ushort_t* __restrict__ Abf,
                                                 ushort_t* __restrict__ Bh,
                                                 ushort_t* __restrict__ W2t,
                                                 double* __restrict__ part,
                                                 int* __restrict__ cnt,
                                                 int* __restrict__ binOf) {
  __shared__ float L[32][260];
  __shared__ double red[256];
  const int bid = blockIdx.x;
  const int tid = threadIdx.x;

  if (bid < 380) {
    // ---- packb: W1^T -> swizzled bf16 tiles [4 cb][95 t][256n x 32k] ----
    const int cb = bid / NT, t = bid % NT;
    const int k0 = t * 32, n0 = cb * 256;
    {
      const int kl = tid >> 3;
      const int nw = tid & 7;
#pragma unroll
      for (int u = 0; u < 8; ++u) {
        const int nl = (nw + u * 8) * 4;
        float4 v = make_float4(0.f, 0.f, 0.f, 0.f);
        if (k0 + kl < K_TOT) v = *(const float4*)(W1 + (size_t)(k0 + kl) * HID + n0 + nl);
        L[kl][nl + 0] = v.x; L[kl][nl + 1] = v.y; L[kl][nl + 2] = v.z; L[kl][nl + 3] = v.w;
      }
    }
    __syncthreads();
    const size_t tileBase = ((size_t)cb * NT + t) * 8192;
    const int n = tid;
#pragma unroll
    for (int q = 0; q < 4; ++q) {
      const int cdata = q ^ ((n >> 1) & 3);
      ushort_t hi[8];
#pragma unroll
      for (int e = 0; e < 8; ++e) {
        const int kl = cdata * 8 + e;
        const float v = (k0 + kl < K_TOT) ? L[kl][n] : 0.f;
        hi[e] = f2bf(v);
      }
      *(bf16x8*)(Bh + tileBase + ((size_t)n * 4 + q) * 8) = *(const bf16x8*)hi;
    }
  } else if (bid < 384) {
    // ---- packw2 ----
    const int k = (bid - 380) * 256 + tid;
#pragma unroll
    for (int o = 0; o < 32; ++o) {
      const float v = (o < OUT_DIM) ? W2[k * OUT_DIM + o] : 0.f;
      W2t[o * HID + k] = f2bf(v);
    }
  } else if (bid < 2432) {
    // ---- convx: 8 rows per block ----
    const int rbase = (bid - 384) * 8;
#pragma unroll
    for (int rr = 0; rr < 8; ++rr) {
      const int row = rbase + rr;
      if (tid < 250) {
#pragma unroll
        for (int ph = 0; ph < 2; ++ph) {
          const int col = ph * 1000 + tid * 4;
          const float4 v = *(const float4*)(x + (size_t)row * IN_DIM + col);
          ushort_t o[4] = { f2bf(v.x), f2bf(v.y), f2bf(v.z), f2bf(v.w) };
          *(bf16x4*)(Abf + (size_t)row * K_PAD + col) = *(const bf16x4*)o;
        }
      } else if (tid < 252) {
        const bf16x8 z = (bf16x8){0, 0, 0, 0, 0, 0, 0, 0};
        *(bf16x8*)(Abf + (size_t)row * K_PAD + K_TOT + (tid - 250) * 8) = z;
      }
    }
  } else if (bid < 2560) {
    // ---- mean_part ----
    const int b = bid - 2432;
    const int g = tid & 31, cs = tid >> 5;
    double acc = 0.0;
#pragma unroll
    for (int it = 0; it < 16; ++it) {
      const int cell = b * 128 + cs + it * 8;
      acc += (double)genes[cell * G_GENES + g];
    }
    red[tid] = acc;
    __syncthreads();
    if (tid < 32) {
      double s = red[tid];
#pragma unroll
      for (int u = 1; u < 8; ++u) s += red[tid + u * 32];
      part[b * 32 + tid] = s;
    }
  } else {
    // ---- bin_count ----
    const int i = (bid - 2560) * 256 + tid;
    const float2 p = ((const float2*)coords)[i];
    const float inv_s = (float)GRID_B / 100.0f;
    const int bx = min(GRID_B - 1, max(0, (int)(p.x * inv_s)));
    const int by = min(GRID_B - 1, max(0, (int)(p.y * inv_s)));
    const int b = by * GRID_B + bx;
    binOf[i] = b;
    atomicAdd(&cnt[b], 1);
  }
}

// ============ block 0: bin prefix-scan | block 1: mean finalize ============
__global__ __launch_bounds__(256) void scan_fin(const int* __restrict__ cnt,
                                                int* __restrict__ binStart,
                                                int* __restrict__ cursor,
                                                const double* __restrict__ part,
                                                float* __restrict__ meanv) {
  const int tid = threadIdx.x;
  if (blockIdx.x == 0) {
    __shared__ int ps[256];
    int s = 0;
    for (int i = 0; i < 64; ++i) s += cnt[tid * 64 + i];
    ps[tid] = s;
    __syncthreads();
    for (int off = 1; off < 256; off <<= 1) {
      const int add = (tid >= off) ? ps[tid - off] : 0;
      __syncthreads();
      ps[tid] += add;
      __syncthreads();
    }
    int run = ps[tid] - s;
    for (int i = 0; i < 64; ++i) {
      const int b = tid * 64 + i;
      binStart[b] = run;
      cursor[b] = run;
      run += cnt[b];
    }
    if (tid == 255) binStart[NBINS] = run;
  } else {
    if (tid < 32) {
      double s = 0.0;
      for (int b = 0; b < 128; ++b) s += part[b * 32 + tid];
      meanv[tid] = (float)(s / (double)N_CELLS);
    }
  }
}

// ---------------- scatter: also build bin-sorted coords stream ----------------
__global__ __launch_bounds__(256) void bin_scatter(const float* __restrict__ coords,
                                                   const int* __restrict__ binOf,
                                                   int* __restrict__ cursor,
                                                   int* __restrict__ binPts,
                                                   float2* __restrict__ sxy) {
  const int i = blockIdx.x * 256 + threadIdx.x;
  const float2 p = ((const float2*)coords)[i];
  const int pos = atomicAdd(&cursor[binOf[i]], 1);
  binPts[pos] = i;
  sxy[pos] = p;
}

// ---------------- kNN in BIN-SORTED order; 256 blocks x 64 -> every CU ----------------
__global__ __launch_bounds__(64) void knn_search(const int* __restrict__ binStart,
                                                 const int* __restrict__ binPts,
                                                 const float2* __restrict__ sxy,
                                                 int* __restrict__ nidx) {
  const int rank = blockIdx.x * 64 + threadIdx.x;
  const int cell = binPts[rank];
  const float2 qv = sxy[rank];
  const float qx = qv.x, qy = qv.y;
  const float sqi = __fadd_rn(__fmul_rn(qx, qx), __fmul_rn(qy, qy));
  const float inv_s = (float)GRID_B / 100.0f;
  const int bx = min(GRID_B - 1, max(0, (int)(qx * inv_s)));
  const int by = min(GRID_B - 1, max(0, (int)(qy * inv_s)));

  unsigned long long kk[8];
#pragma unroll
  for (int i = 0; i < 8; ++i) kk[i] = ~0ull;

  auto scan_seg = [&](int s, int e) {
    for (int p = s; p < e; ++p) {
      const float2 pc = sxy[p];
      const int j = binPts[p];
      const float sqj = __fadd_rn(__fmul_rn(pc.x, pc.x), __fmul_rn(pc.y, pc.y));
      const float dot = __fmaf_rn(qy, pc.y, __fmul_rn(qx, pc.x));
      const float d2  = __fsub_rn(__fadd_rn(sqi, sqj), __fmul_rn(2.0f, dot));
      unsigned int sb = __float_as_uint(d2);
      sb = (sb & 0x80000000u) ? ~sb : (sb | 0x80000000u);
      unsigned long long key = ((unsigned long long)sb << 32) | (unsigned int)j;
      if (key < kk[7]) {
#pragma unroll
        for (int q2 = 0; q2 < 8; ++q2) {
          const bool lt = key < kk[q2];
          const unsigned long long tmp = kk[q2];
          kk[q2] = lt ? key : kk[q2];
          key = lt ? tmp : key;
        }
      }
    }
  };

  bool done = false;
  for (int r = 0; r < GRID_B; ++r) {
    if (!done) {
      if (r == 0) {
        const int b = by * GRID_B + bx;
        scan_seg(binStart[b], binStart[b + 1]);
      } else {
        const int xlo = max(0, bx - r), xhi = min(GRID_B - 1, bx + r);
        if (by - r >= 0) {
          const int b0 = (by - r) * GRID_B;
          scan_seg(binStart[b0 + xlo], binStart[b0 + xhi + 1]);
        }
        if (by + r < GRID_B) {
          const int b0 = (by + r) * GRID_B;
          scan_seg(binStart[b0 + xlo], binStart[b0 + xhi + 1]);
        }
        for (int dy = -r + 1; dy <= r - 1; ++dy) {
          const int yy = by + dy;
          if (yy < 0 || yy >= GRID_B) continue;
          if (bx - r >= 0) { const int b = yy * GRID_B + bx - r; scan_seg(binStart[b], binStart[b + 1]); }
          if (bx + r < GRID_B) { const int b = yy * GRID_B + bx + r; scan_seg(binStart[b], binStart[b + 1]); }
        }
      }
      if (kk[7] != ~0ull) {
        const unsigned int sb = (unsigned int)(kk[7] >> 32);
        const float wd2 = __uint_as_float((sb & 0x80000000u) ? (sb ^ 0x80000000u) : ~sb);
        const float bnd = (float)r * SCELL;
        if (wd2 < bnd * bnd * 0.998f - 0.05f) done = true;
      }
    }
    if (!__any(!done)) break;
  }
#pragma unroll
  for (int i = 0; i < 8; ++i) nidx[cell * 8 + i] = (int)(kk[i] & 0xFFFFFFFFu);
}

// ---------------- Gram -> transposed [64][N_CELLS] layout ----------------
__global__ __launch_bounds__(256) void gram_kernel(const float* __restrict__ genes,
                                                   const float* __restrict__ meanv,
                                                   const int* __restrict__ nidx,
                                                   float* __restrict__ GwsT) {
  const int wv = threadIdx.x >> 6, lane = threadIdx.x & 63;
  const int bidl = (blockIdx.x & 7) * 512 + (blockIdx.x >> 3);   // bijective 4096
  const int cell = bidl * 4 + wv;
  __shared__ float A[4][8][33];
#pragma unroll
  for (int q = 0; q < 4; ++q) {
    const int e = lane + (q << 6);
    const int n = e >> 5, g = e & 31;
    const int src = nidx[cell * 8 + n];
    A[wv][n][g] = (genes[src * G_GENES + g] - meanv[g]) * CSCALE;
  }
  __syncthreads();
  const int i = lane >> 3, j = lane & 7;
  float acc = 0.f;
#pragma unroll
  for (int g = 0; g < 32; ++g) acc = fmaf(A[wv][i][g], A[wv][j][g], acc);
  GwsT[(size_t)lane * N_CELLS + cell] = acc;
}

// ---------------- 8x8 Jacobi: lane=cell, coalesced I/O, fast t/c/s ----------------
__global__ __launch_bounds__(64) void jacobi_kernel(const float* __restrict__ GwsT,
                                                    float* __restrict__ VwsT,
                                                    float* __restrict__ lamT) {
  const int cell = blockIdx.x * 64 + threadIdx.x;
  float Gm[8][8], V[8][8];
#pragma unroll
  for (int e = 0; e < 64; ++e) Gm[e >> 3][e & 7] = GwsT[(size_t)e * N_CELLS + cell];
#pragma unroll
  for (int i = 0; i < 8; ++i)
#pragma unroll
    for (int j = 0; j < 8; ++j) V[i][j] = (i == j) ? 1.0f : 0.0f;

  for (int sweep = 0; sweep < 5; ++sweep) {
#pragma unroll
    for (int p = 0; p < 7; ++p) {
#pragma unroll
      for (int q = p + 1; q < 8; ++q) {
        const float apq = Gm[p][q];
        const float app = Gm[p][p], aqq = Gm[q][q];
        float t;
        if (apq != 0.0f) {
          const float tau = (aqq - app) * __builtin_amdgcn_rcpf(2.0f * apq);
          const float r = sqrtf(fmaf(tau, tau, 1.0f));
          t = copysignf(1.0f, tau) * __builtin_amdgcn_rcpf(fabsf(tau) + r);
        } else {
          t = 0.0f;
        }
        const float c = __builtin_amdgcn_rsqf(fmaf(t, t, 1.0f));
        const float s = t * c;
#pragma unroll
        for (int r2 = 0; r2 < 8; ++r2) {
          const float gp = Gm[p][r2], gq = Gm[q][r2];
          Gm[p][r2] = fmaf(c, gp, -s * gq);
          Gm[q][r2] = fmaf(s, gp,  c * gq);
        }
#pragma unroll
        for (int r2 = 0; r2 < 8; ++r2) {
          const float gp = Gm[r2][p], gq = Gm[r2][q];
          Gm[r2][p] = fmaf(c, gp, -s * gq);
          Gm[r2][q] = fmaf(s, gp,  c * gq);
        }
#pragma unroll
        for (int r2 = 0; r2 < 8; ++r2) {
          const float vp = V[r2][p], vq = V[r2][q];
          V[r2][p] = fmaf(c, vp, -s * vq);
          V[r2][q] = fmaf(s, vp,  c * vq);
        }
      }
    }
  }
#pragma unroll
  for (int e = 0; e < 64; ++e) VwsT[(size_t)e * N_CELLS + cell] = V[e >> 3][e & 7];
#pragma unroll
  for (int m = 0; m < 8; ++m) lamT[(size_t)m * N_CELLS + cell] = Gm[m][m];
}

// ---------------- covet (bf16) -> Abf cols 2000..3023 ----------------
__global__ __launch_bounds__(256) void recon_kernel(const float* __restrict__ genes,
                                                    const float* __restrict__ meanv,
                                                    const int* __restrict__ nidx,
                                                    const float* __restrict__ VwsT,
                                                    const float* __restrict__ lamT,
                                                    ushort_t* __restrict__ Abf) {
  const int wv = threadIdx.x >> 6, lane = threadIdx.x & 63;
  const int cell = blockIdx.x * 4 + wv;
  __shared__ float A[4][8][33];
  __shared__ float Ws[4][8][33];
  __shared__ float Vs[4][64];
  __shared__ float lamS[4][8];
#pragma unroll
  for (int q = 0; q < 4; ++q) {
    const int e = lane + (q << 6);
    const int n = e >> 5, g = e & 31;
    const int src = nidx[cell * 8 + n];
    A[wv][n][g] = (genes[src * G_GENES + g] - meanv[g]) * CSCALE;
  }
  Vs[wv][lane] = VwsT[(size_t)lane * N_CELLS + cell];
  if (lane < 8) lamS[wv][lane] = lamT[(size_t)lane * N_CELLS + cell];
  __syncthreads();

  float maxl = 0.f;
#pragma unroll
  for (int m = 0; m < 8; ++m) maxl = fmaxf(maxl, lamS[wv][m]);
  const float thr = maxl * 1e-8f;

#pragma unroll
  for (int q = 0; q < 4; ++q) {
    const int e = lane + (q << 6);
    const int m = e >> 5, g = e & 31;
    float acc = 0.f;
#pragma unroll
    for (int i = 0; i < 8; ++i) acc = fmaf(Vs[wv][i * 8 + m], A[wv][i][g], acc);
    const float l = lamS[wv][m];
    const float scm = (l > thr) ? sqrtf(1.0f / sqrtf(l)) : 0.0f;
    Ws[wv][m][g] = acc * scm;
  }
  __syncthreads();
  ushort_t* dst = Abf + (size_t)cell * K_PAD + IN_DIM;
#pragma unroll
  for (int r = 0; r < 16; ++r) {
    const int o = (r << 6) + lane;
    const int g = o >> 5, hh = o & 31;
    float acc = 0.f;
#pragma unroll
    for (int m = 0; m < 8; ++m) acc = fmaf(Ws[wv][m][g], Ws[wv][m][hh], acc);
    dst[o] = f2bf(acc);
  }
}

// ---------------- GEMM1: same 3-buf/vmcnt skeleton, 4 waves x (128x64) wave-tile ----------------
// 128x256 block, 256 threads. Per iter/thread: 2 A-glds + 4 B-glds = 6 -> vmcnt(6).
// Per wave: 12 ds_read_b128 -> 32 MFMA (2.67 MFMA/read vs 2.0 before).
__global__ __launch_bounds__(256, 2) void gemm1_kernel(const ushort_t* __restrict__ Abf,
                                                       const ushort_t* __restrict__ Bh,
                                                       const float* __restrict__ b1,
                                                       ushort_t* __restrict__ h) {
  __shared__ ushort_t As[3][4096];   // 128 rows x 32k, chunk-swizzled, 24 KB
  __shared__ ushort_t Bs[3][8192];   // 256 rows x 32k, chunk-swizzled, 48 KB

  const int tid = threadIdx.x;
  const int id  = blockIdx.x;
  const int xcd = id & 7, local = id >> 3;
  const int rb  = (xcd << 4) + (local & 15);
  const int cb  = local >> 4;
  const int row0 = rb << 7, col0 = cb << 8;

  const int lane = tid & 63, wv = tid >> 6;
  const int n_base = wv << 6;              // wave owns all 128 rows x 64 cols
  const int l15 = lane & 15, l4 = lane >> 4;

  // A staging: chunks c = tid and tid+256; r = c>>2, cpos = c&3 (same for both)
  const int ar0 = tid >> 2, acpos = tid & 3;
  const int acdata = acpos ^ ((ar0 >> 1) & 3);   // ((r+64)>>1)&3 == (r>>1)&3
  const ushort_t* aptr0 = Abf + (size_t)(row0 + ar0) * K_PAD + acdata * 8;
  const ushort_t* aptr1 = Abf + (size_t)(row0 + ar0 + 64) * K_PAD + acdata * 8;
  // B staging: 4 linear chunks from packed tile
  const ushort_t* bptr = Bh + (size_t)cb * NT * 8192 + tid * 8;

  int aoff[8], boff[4];
#pragma unroll
  for (int i = 0; i < 8; ++i) {
    const int r = i * 16 + l15;
    aoff[i] = r * 32 + (l4 ^ ((r >> 1) & 3)) * 8;
  }
#pragma unroll
  for (int j = 0; j < 4; ++j) {
    const int r = n_base + j * 16 + l15;
    boff[j] = r * 32 + (l4 ^ ((r >> 1) & 3)) * 8;
  }

  f32x4 acc[8][4];
#pragma unroll
  for (int i = 0; i < 8; ++i)
#pragma unroll
    for (int j = 0; j < 4; ++j) acc[i][j] = (f32x4){0.f, 0.f, 0.f, 0.f};

  auto prefetch = [&](int buf) {
    glds16(aptr0, &As[buf][tid * 8]);
    glds16(aptr1, &As[buf][tid * 8 + 2048]);
    glds16(bptr,        &Bs[buf][tid * 8]);
    glds16(bptr + 2048, &Bs[buf][tid * 8 + 2048]);
    glds16(bptr + 4096, &Bs[buf][tid * 8 + 4096]);
    glds16(bptr + 6144, &Bs[buf][tid * 8 + 6144]);
    aptr0 += 32;
    aptr1 += 32;
    bptr += 8192;
  };
  auto compute = [&](int buf) {
    bf16x8 ah[8], bh[4];
#pragma unroll
    for (int i = 0; i < 8; ++i) ah[i] = *(const bf16x8*)(&As[buf][aoff[i]]);
#pragma unroll
    for (int j = 0; j < 4; ++j) bh[j] = *(const bf16x8*)(&Bs[buf][boff[j]]);
#pragma unroll
    for (int i = 0; i < 8; ++i)
#pragma unroll
      for (int j = 0; j < 4; ++j)
        acc[i][j] = __builtin_amdgcn_mfma_f32_16x16x32_bf16(ah[i], bh[j], acc[i][j], 0, 0, 0);
  };

  prefetch(0);
  prefetch(1);
  asm volatile("s_waitcnt vmcnt(6)" ::: "memory");   // tile 0's 6 loads landed
  __builtin_amdgcn_s_barrier();
  __builtin_amdgcn_sched_barrier(0);

#define STEP(BUFC, BUFP) { prefetch(BUFP); compute(BUFC); \
    asm volatile("s_waitcnt vmcnt(6)" ::: "memory"); \
    __builtin_amdgcn_s_barrier(); \
    __builtin_amdgcn_sched_barrier(0); }
  for (int tt = 0; tt < 31; ++tt) {
    STEP(0, 2)
    STEP(1, 0)
    STEP(2, 1)
  }
#undef STEP
  compute(0);   // t = 93
  asm volatile("s_waitcnt vmcnt(0)" ::: "memory");
  __builtin_amdgcn_s_barrier();
  __builtin_amdgcn_sched_barrier(0);
  compute(1);   // t = 94

  float bb[4];
#pragma unroll
  for (int j = 0; j < 4; ++j) bb[j] = b1[col0 + n_base + j * 16 + l15];
#pragma unroll
  for (int i = 0; i < 8; ++i) {
    const int rbase = row0 + i * 16 + l4 * 4;
#pragma unroll
    for (int j = 0; j < 4; ++j) {
      const int c = col0 + n_base + j * 16 + l15;
#pragma unroll
      for (int q = 0; q < 4; ++q) {
        const float v = fmaxf(acc[i][j][q] + bb[j], 0.f);
        h[(size_t)(rbase + q) * HID + c] = f2bf(v);
      }
    }
  }
}

// ---------------- GEMM2: out = h @ W2 + b2 via bf16 MFMA ----------------
__global__ __launch_bounds__(256) void gemm2_kernel(const ushort_t* __restrict__ h,
                                                    const ushort_t* __restrict__ W2t,
                                                    const float* __restrict__ b2,
                                                    float* __restrict__ out) {
  const int tid = threadIdx.x;
  const int lane = tid & 63, wv = tid >> 6;
  const int rowt = wv & 1, colt = wv >> 1;
  const int l15 = lane & 15, l4 = lane >> 4;
  const int row0 = blockIdx.x * 32 + rowt * 16;
  const int col  = colt * 16 + l15;

  f32x4 acc = (f32x4){0.f, 0.f, 0.f, 0.f};
  const ushort_t* ha = h + (size_t)(row0 + l15) * HID + l4 * 8;
  const ushort_t* wb = W2t + (size_t)col * HID + l4 * 8;
#pragma unroll 8
  for (int k0 = 0; k0 < HID; k0 += 32) {
    const bf16x8 av = *(const bf16x8*)(ha + k0);
    const bf16x8 bv = *(const bf16x8*)(wb + k0);
    acc = __builtin_amdgcn_mfma_f32_16x16x32_bf16(av, bv, acc, 0, 0, 0);
  }
  if (col < OUT_DIM) {
    const float bias = b2[col];
#pragma unroll
    for (int q = 0; q < 4; ++q) {
      const int r = row0 + l4 * 4 + q;
      out[(size_t)r * OUT_DIM + col] = acc[q] + bias;
    }
  }
}

extern "C" void kernel_launch(void* const* d_in, const int* in_sizes, int n_in,
                              void* d_out, int out_size, void* d_ws, size_t ws_size,
                              hipStream_t stream) {
  (void)in_sizes; (void)n_in; (void)out_size;
  const float* x      = (const float*)d_in[0];
  const float* coords = (const float*)d_in[1];
  const float* genes  = (const float*)d_in[2];
  const float* W1     = (const float*)d_in[3];
  const float* b1     = (const float*)d_in[4];
  const float* W2     = (const float*)d_in[5];
  const float* b2     = (const float*)d_in[6];
  float* out = (float*)d_out;

  char* ws = (char*)d_ws;
  size_t off = 0;
  auto alloc = [&](size_t bytes) -> void* {
    void* p = ws + off;
    off = (off + bytes + 255) & ~(size_t)255;
    return p;
  };
  ushort_t* Abf    = (ushort_t*)alloc((size_t)N_CELLS * K_PAD * 2);   // 99.6 MB
  ushort_t* hbf    = (ushort_t*)alloc((size_t)N_CELLS * HID * 2);     // 33.5 MB
  ushort_t* Bh     = (ushort_t*)alloc((size_t)4 * NT * 8192 * 2);     // 6.2 MB
  ushort_t* W2t    = (ushort_t*)alloc((size_t)32 * HID * 2);          // 64 KB
  float*    GwsT   = (float*)alloc((size_t)64 * N_CELLS * 4);
  float*    VwsT   = (float*)alloc((size_t)64 * N_CELLS * 4);
  float*    lamT   = (float*)alloc((size_t)8 * N_CELLS * 4);
  int*      nidx   = (int*)alloc((size_t)N_CELLS * 8 * 4);
  double*   part   = (double*)alloc((size_t)128 * 32 * 8);
  float*    meanv  = (float*)alloc(G_GENES * 4);
  int*      binCnt = (int*)alloc((size_t)NBINS * 4);
  int*      binSt  = (int*)alloc((size_t)(NBINS + 1) * 4);
  int*      cursor = (int*)alloc((size_t)NBINS * 4);
  int*      binOf  = (int*)alloc((size_t)N_CELLS * 4);
  int*      binPts = (int*)alloc((size_t)N_CELLS * 4);
  float2*   sxy    = (float2*)alloc((size_t)N_CELLS * 8);
  if (off > ws_size) return;

  hipMemsetAsync(binCnt, 0, (size_t)NBINS * 4, stream);

  hipLaunchKernelGGL(fused_pre,   dim3(2624),  dim3(256), 0, stream,
                     x, W1, W2, genes, coords, Abf, Bh, W2t, part, binCnt, binOf);
  hipLaunchKernelGGL(scan_fin,    dim3(2),     dim3(256), 0, stream, binCnt, binSt, cursor, part, meanv);
  hipLaunchKernelGGL(bin_scatter, dim3(64),    dim3(256), 0, stream, coords, binOf, cursor, binPts, sxy);
  hipLaunchKernelGGL(knn_search,  dim3(256),   dim3(64),  0, stream, binSt, binPts, sxy, nidx);
  hipLaunchKernelGGL(gram_kernel, dim3(4096),  dim3(256), 0, stream, genes, meanv, nidx, GwsT);
  hipLaunchKernelGGL(jacobi_kernel, dim3(256), dim3(64),  0, stream, GwsT, VwsT, lamT);
  hipLaunchKernelGGL(recon_kernel,  dim3(4096), dim3(256), 0, stream, genes, meanv, nidx, VwsT, lamT, Abf);
  hipLaunchKernelGGL(gemm1_kernel,  dim3(512),  dim3(256), 0, stream, Abf, Bh, b1, hbf);
  hipLaunchKernelGGL(gemm2_kernel,  dim3(512),  dim3(256), 0, stream, hbf, W2t, b2, out);
}

// Round 14
// 266.919 us; speedup vs baseline: 1.0086x; 1.0086x over previous
//
#include <hip/hip_runtime.h>
#include <hip/hip_bf16.h>
#include <math.h>

#define N_CELLS 16384
#define G_GENES 32
#define IN_DIM  2000
#define HID     1024
#define OUT_DIM 30
#define K_TOT   3024      // IN_DIM + 1024
#define K_PAD   3040      // 95 * 32
#define NT      95
#define GRID_B  128
#define NBINS   (GRID_B * GRID_B)
#define SCELL   (100.0f / (float)GRID_B)
#define CSCALE  0.37796447300922722721f   // 1/sqrt(7)

typedef unsigned short ushort_t;
typedef __attribute__((ext_vector_type(8))) short bf16x8;
typedef __attribute__((ext_vector_type(4))) short bf16x4;
typedef __attribute__((ext_vector_type(4))) float f32x4;

__device__ __forceinline__ ushort_t f2bf(float v) {
  return __builtin_bit_cast(ushort_t, __float2bfloat16(v));
}

// global_load_lds: 16B per lane, LDS dest = wave-uniform base + lane*16
__device__ __forceinline__ void glds16(const void* g, void* l) {
  __builtin_amdgcn_global_load_lds(
      (const __attribute__((address_space(1))) unsigned int*)g,
      (__attribute__((address_space(3))) unsigned int*)l, 16, 0, 0);
}

// ============ fused pre-pass: packb | packw2 | convx | mean_part | bin_count ============
__global__ __launch_bounds__(256) void fused_pre(const float* __restrict__ x,
                                                 const float* __restrict__ W1,
                                                 const float* __restrict__ W2,
                                                 const float* __restrict__ genes,
                                                 const float* __restrict__ coords,
                                                 ushort_t* __restrict__ Abf,
                                                 ushort_t* __restrict__ Bh,
                                                 ushort_t* __restrict__ W2t,
                                                 double* __restrict__ part,
                                                 int* __restrict__ cnt,
                                                 int* __restrict__ binOf) {
  __shared__ float L[32][260];
  __shared__ double red[256];
  const int bid = blockIdx.x;
  const int tid = threadIdx.x;

  if (bid < 380) {
    // ---- packb: W1^T -> swizzled bf16 tiles [4 cb][95 t][256n x 32k] ----
    const int cb = bid / NT, t = bid % NT;
    const int k0 = t * 32, n0 = cb * 256;
    {
      const int kl = tid >> 3;
      const int nw = tid & 7;
#pragma unroll
      for (int u = 0; u < 8; ++u) {
        const int nl = (nw + u * 8) * 4;
        float4 v = make_float4(0.f, 0.f, 0.f, 0.f);
        if (k0 + kl < K_TOT) v = *(const float4*)(W1 + (size_t)(k0 + kl) * HID + n0 + nl);
        L[kl][nl + 0] = v.x; L[kl][nl + 1] = v.y; L[kl][nl + 2] = v.z; L[kl][nl + 3] = v.w;
      }
    }
    __syncthreads();
    const size_t tileBase = ((size_t)cb * NT + t) * 8192;
    const int n = tid;
#pragma unroll
    for (int q = 0; q < 4; ++q) {
      const int cdata = q ^ ((n >> 1) & 3);
      ushort_t hi[8];
#pragma unroll
      for (int e = 0; e < 8; ++e) {
        const int kl = cdata * 8 + e;
        const float v = (k0 + kl < K_TOT) ? L[kl][n] : 0.f;
        hi[e] = f2bf(v);
      }
      *(bf16x8*)(Bh + tileBase + ((size_t)n * 4 + q) * 8) = *(const bf16x8*)hi;
    }
  } else if (bid < 384) {
    // ---- packw2 ----
    const int k = (bid - 380) * 256 + tid;
#pragma unroll
    for (int o = 0; o < 32; ++o) {
      const float v = (o < OUT_DIM) ? W2[k * OUT_DIM + o] : 0.f;
      W2t[o * HID + k] = f2bf(v);
    }
  } else if (bid < 2432) {
    // ---- convx: 8 rows per block ----
    const int rbase = (bid - 384) * 8;
#pragma unroll
    for (int rr = 0; rr < 8; ++rr) {
      const int row = rbase + rr;
      if (tid < 250) {
#pragma unroll
        for (int ph = 0; ph < 2; ++ph) {
          const int col = ph * 1000 + tid * 4;
          const float4 v = *(const float4*)(x + (size_t)row * IN_DIM + col);
          ushort_t o[4] = { f2bf(v.x), f2bf(v.y), f2bf(v.z), f2bf(v.w) };
          *(bf16x4*)(Abf + (size_t)row * K_PAD + col) = *(const bf16x4*)o;
        }
      } else if (tid < 252) {
        const bf16x8 z = (bf16x8){0, 0, 0, 0, 0, 0, 0, 0};
        *(bf16x8*)(Abf + (size_t)row * K_PAD + K_TOT + (tid - 250) * 8) = z;
      }
    }
  } else if (bid < 2560) {
    // ---- mean_part ----
    const int b = bid - 2432;
    const int g = tid & 31, cs = tid >> 5;
    double acc = 0.0;
#pragma unroll
    for (int it = 0; it < 16; ++it) {
      const int cell = b * 128 + cs + it * 8;
      acc += (double)genes[cell * G_GENES + g];
    }
    red[tid] = acc;
    __syncthreads();
    if (tid < 32) {
      double s = red[tid];
#pragma unroll
      for (int u = 1; u < 8; ++u) s += red[tid + u * 32];
      part[b * 32 + tid] = s;
    }
  } else {
    // ---- bin_count ----
    const int i = (bid - 2560) * 256 + tid;
    const float2 p = ((const float2*)coords)[i];
    const float inv_s = (float)GRID_B / 100.0f;
    const int bx = min(GRID_B - 1, max(0, (int)(p.x * inv_s)));
    const int by = min(GRID_B - 1, max(0, (int)(p.y * inv_s)));
    const int b = by * GRID_B + bx;
    binOf[i] = b;
    atomicAdd(&cnt[b], 1);
  }
}

// ============ block 0: bin prefix-scan | block 1: mean finalize ============
__global__ __launch_bounds__(256) void scan_fin(const int* __restrict__ cnt,
                                                int* __restrict__ binStart,
                                                int* __restrict__ cursor,
                                                const double* __restrict__ part,
                                                float* __restrict__ meanv) {
  const int tid = threadIdx.x;
  if (blockIdx.x == 0) {
    __shared__ int ps[256];
    int s = 0;
    for (int i = 0; i < 64; ++i) s += cnt[tid * 64 + i];
    ps[tid] = s;
    __syncthreads();
    for (int off = 1; off < 256; off <<= 1) {
      const int add = (tid >= off) ? ps[tid - off] : 0;
      __syncthreads();
      ps[tid] += add;
      __syncthreads();
    }
    int run = ps[tid] - s;
    for (int i = 0; i < 64; ++i) {
      const int b = tid * 64 + i;
      binStart[b] = run;
      cursor[b] = run;
      run += cnt[b];
    }
    if (tid == 255) binStart[NBINS] = run;
  } else {
    if (tid < 32) {
      double s = 0.0;
      for (int b = 0; b < 128; ++b) s += part[b * 32 + tid];
      meanv[tid] = (float)(s / (double)N_CELLS);
    }
  }
}

// ---------------- scatter: also build bin-sorted coords stream ----------------
__global__ __launch_bounds__(256) void bin_scatter(const float* __restrict__ coords,
                                                   const int* __restrict__ binOf,
                                                   int* __restrict__ cursor,
                                                   int* __restrict__ binPts,
                                                   float2* __restrict__ sxy) {
  const int i = blockIdx.x * 256 + threadIdx.x;
  const float2 p = ((const float2*)coords)[i];
  const int pos = atomicAdd(&cursor[binOf[i]], 1);
  binPts[pos] = i;
  sxy[pos] = p;
}

// ---------------- kNN in BIN-SORTED order; 256 blocks x 64 -> every CU ----------------
__global__ __launch_bounds__(64) void knn_search(const int* __restrict__ binStart,
                                                 const int* __restrict__ binPts,
                                                 const float2* __restrict__ sxy,
                                                 int* __restrict__ nidx) {
  const int rank = blockIdx.x * 64 + threadIdx.x;
  const int cell = binPts[rank];
  const float2 qv = sxy[rank];
  const float qx = qv.x, qy = qv.y;
  const float sqi = __fadd_rn(__fmul_rn(qx, qx), __fmul_rn(qy, qy));
  const float inv_s = (float)GRID_B / 100.0f;
  const int bx = min(GRID_B - 1, max(0, (int)(qx * inv_s)));
  const int by = min(GRID_B - 1, max(0, (int)(qy * inv_s)));

  unsigned long long kk[8];
#pragma unroll
  for (int i = 0; i < 8; ++i) kk[i] = ~0ull;

  auto scan_seg = [&](int s, int e) {
    for (int p = s; p < e; ++p) {
      const float2 pc = sxy[p];
      const int j = binPts[p];
      const float sqj = __fadd_rn(__fmul_rn(pc.x, pc.x), __fmul_rn(pc.y, pc.y));
      const float dot = __fmaf_rn(qy, pc.y, __fmul_rn(qx, pc.x));
      const float d2  = __fsub_rn(__fadd_rn(sqi, sqj), __fmul_rn(2.0f, dot));
      unsigned int sb = __float_as_uint(d2);
      sb = (sb & 0x80000000u) ? ~sb : (sb | 0x80000000u);
      unsigned long long key = ((unsigned long long)sb << 32) | (unsigned int)j;
      if (key < kk[7]) {
#pragma unroll
        for (int q2 = 0; q2 < 8; ++q2) {
          const bool lt = key < kk[q2];
          const unsigned long long tmp = kk[q2];
          kk[q2] = lt ? key : kk[q2];
          key = lt ? tmp : key;
        }
      }
    }
  };

  bool done = false;
  for (int r = 0; r < GRID_B; ++r) {
    if (!done) {
      if (r == 0) {
        const int b = by * GRID_B + bx;
        scan_seg(binStart[b], binStart[b + 1]);
      } else {
        const int xlo = max(0, bx - r), xhi = min(GRID_B - 1, bx + r);
        if (by - r >= 0) {
          const int b0 = (by - r) * GRID_B;
          scan_seg(binStart[b0 + xlo], binStart[b0 + xhi + 1]);
        }
        if (by + r < GRID_B) {
          const int b0 = (by + r) * GRID_B;
          scan_seg(binStart[b0 + xlo], binStart[b0 + xhi + 1]);
        }
        for (int dy = -r + 1; dy <= r - 1; ++dy) {
          const int yy = by + dy;
          if (yy < 0 || yy >= GRID_B) continue;
          if (bx - r >= 0) { const int b = yy * GRID_B + bx - r; scan_seg(binStart[b], binStart[b + 1]); }
          if (bx + r < GRID_B) { const int b = yy * GRID_B + bx + r; scan_seg(binStart[b], binStart[b + 1]); }
        }
      }
      if (kk[7] != ~0ull) {
        const unsigned int sb = (unsigned int)(kk[7] >> 32);
        const float wd2 = __uint_as_float((sb & 0x80000000u) ? (sb ^ 0x80000000u) : ~sb);
        const float bnd = (float)r * SCELL;
        if (wd2 < bnd * bnd * 0.998f - 0.05f) done = true;
      }
    }
    if (!__any(!done)) break;
  }
#pragma unroll
  for (int i = 0; i < 8; ++i) nidx[cell * 8 + i] = (int)(kk[i] & 0xFFFFFFFFu);
}

// ---------------- Gram -> transposed [64][N_CELLS]; float4 gather ----------------
__global__ __launch_bounds__(256) void gram_kernel(const float* __restrict__ genes,
                                                   const float* __restrict__ meanv,
                                                   const int* __restrict__ nidx,
                                                   float* __restrict__ GwsT) {
  const int wv = threadIdx.x >> 6, lane = threadIdx.x & 63;
  const int bidl = (blockIdx.x & 7) * 512 + (blockIdx.x >> 3);   // bijective 4096
  const int cell = bidl * 4 + wv;
  __shared__ float A[4][8][36];   // stride 36: 16B-aligned float4 writes, banks 4i
  {
    const int n = lane >> 3;            // 0..7 neighbor row
    const int c = (lane & 7) << 2;      // 0,4,..,28
    const int src = nidx[cell * 8 + n];
    const float4 v = *(const float4*)(genes + (size_t)src * G_GENES + c);
    float o[4] = { (v.x - meanv[c + 0]) * CSCALE, (v.y - meanv[c + 1]) * CSCALE,
                   (v.z - meanv[c + 2]) * CSCALE, (v.w - meanv[c + 3]) * CSCALE };
    *(float4*)&A[wv][n][c] = *(const float4*)o;
  }
  __syncthreads();
  const int i = lane >> 3, j = lane & 7;
  float acc = 0.f;
#pragma unroll
  for (int g = 0; g < 32; ++g) acc = fmaf(A[wv][i][g], A[wv][j][g], acc);
  GwsT[(size_t)lane * N_CELLS + cell] = acc;
}

// ---------------- 8x8 Jacobi: lane=cell, coalesced I/O, fast t/c/s ----------------
__global__ __launch_bounds__(64) void jacobi_kernel(const float* __restrict__ GwsT,
                                                    float* __restrict__ VwsT,
                                                    float* __restrict__ lamT) {
  const int cell = blockIdx.x * 64 + threadIdx.x;
  float Gm[8][8], V[8][8];
#pragma unroll
  for (int e = 0; e < 64; ++e) Gm[e >> 3][e & 7] = GwsT[(size_t)e * N_CELLS + cell];
#pragma unroll
  for (int i = 0; i < 8; ++i)
#pragma unroll
    for (int j = 0; j < 8; ++j) V[i][j] = (i == j) ? 1.0f : 0.0f;

  for (int sweep = 0; sweep < 5; ++sweep) {
#pragma unroll
    for (int p = 0; p < 7; ++p) {
#pragma unroll
      for (int q = p + 1; q < 8; ++q) {
        const float apq = Gm[p][q];
        const float app = Gm[p][p], aqq = Gm[q][q];
        float t;
        if (apq != 0.0f) {
          const float tau = (aqq - app) * __builtin_amdgcn_rcpf(2.0f * apq);
          const float r = sqrtf(fmaf(tau, tau, 1.0f));
          t = copysignf(1.0f, tau) * __builtin_amdgcn_rcpf(fabsf(tau) + r);
        } else {
          t = 0.0f;
        }
        const float c = __builtin_amdgcn_rsqf(fmaf(t, t, 1.0f));
        const float s = t * c;
#pragma unroll
        for (int r2 = 0; r2 < 8; ++r2) {
          const float gp = Gm[p][r2], gq = Gm[q][r2];
          Gm[p][r2] = fmaf(c, gp, -s * gq);
          Gm[q][r2] = fmaf(s, gp,  c * gq);
        }
#pragma unroll
        for (int r2 = 0; r2 < 8; ++r2) {
          const float gp = Gm[r2][p], gq = Gm[r2][q];
          Gm[r2][p] = fmaf(c, gp, -s * gq);
          Gm[r2][q] = fmaf(s, gp,  c * gq);
        }
#pragma unroll
        for (int r2 = 0; r2 < 8; ++r2) {
          const float vp = V[r2][p], vq = V[r2][q];
          V[r2][p] = fmaf(c, vp, -s * vq);
          V[r2][q] = fmaf(s, vp,  c * vq);
        }
      }
    }
  }
#pragma unroll
  for (int e = 0; e < 64; ++e) VwsT[(size_t)e * N_CELLS + cell] = V[e >> 3][e & 7];
#pragma unroll
  for (int m = 0; m < 8; ++m) lamT[(size_t)m * N_CELLS + cell] = Gm[m][m];
}

// ---------------- covet (bf16) -> Abf cols 2000..3023; float4 gather ----------------
__global__ __launch_bounds__(256) void recon_kernel(const float* __restrict__ genes,
                                                    const float* __restrict__ meanv,
                                                    const int* __restrict__ nidx,
                                                    const float* __restrict__ VwsT,
                                                    const float* __restrict__ lamT,
                                                    ushort_t* __restrict__ Abf) {
  const int wv = threadIdx.x >> 6, lane = threadIdx.x & 63;
  const int cell = blockIdx.x * 4 + wv;
  __shared__ float A[4][8][36];   // stride 36: aligned float4
  __shared__ float Ws[4][8][33];
  __shared__ float Vs[4][64];
  __shared__ float lamS[4][8];
  {
    const int n = lane >> 3;
    const int c = (lane & 7) << 2;
    const int src = nidx[cell * 8 + n];
    const float4 v = *(const float4*)(genes + (size_t)src * G_GENES + c);
    float o[4] = { (v.x - meanv[c + 0]) * CSCALE, (v.y - meanv[c + 1]) * CSCALE,
                   (v.z - meanv[c + 2]) * CSCALE, (v.w - meanv[c + 3]) * CSCALE };
    *(float4*)&A[wv][n][c] = *(const float4*)o;
  }
  Vs[wv][lane] = VwsT[(size_t)lane * N_CELLS + cell];
  if (lane < 8) lamS[wv][lane] = lamT[(size_t)lane * N_CELLS + cell];
  __syncthreads();

  float maxl = 0.f;
#pragma unroll
  for (int m = 0; m < 8; ++m) maxl = fmaxf(maxl, lamS[wv][m]);
  const float thr = maxl * 1e-8f;

#pragma unroll
  for (int q = 0; q < 4; ++q) {
    const int e = lane + (q << 6);
    const int m = e >> 5, g = e & 31;
    float acc = 0.f;
#pragma unroll
    for (int i = 0; i < 8; ++i) acc = fmaf(Vs[wv][i * 8 + m], A[wv][i][g], acc);
    const float l = lamS[wv][m];
    const float scm = (l > thr) ? sqrtf(1.0f / sqrtf(l)) : 0.0f;
    Ws[wv][m][g] = acc * scm;
  }
  __syncthreads();
  ushort_t* dst = Abf + (size_t)cell * K_PAD + IN_DIM;
#pragma unroll
  for (int r = 0; r < 16; ++r) {
    const int o = (r << 6) + lane;
    const int g = o >> 5, hh = o & 31;
    float acc = 0.f;
#pragma unroll
    for (int m = 0; m < 8; ++m) acc = fmaf(Ws[wv][m][g], Ws[wv][m][hh], acc);
    dst[o] = f2bf(acc);
  }
}

// ---------------- GEMM1 (round-8 proven structure, FROZEN): pure-glds pipeline ----------------
// 128x256 tile, 8 waves of 64x64, BK=32, A+B 3 buffers, vmcnt(3)+raw barrier per iter.
__global__ __launch_bounds__(512, 4) void gemm1_kernel(const ushort_t* __restrict__ Abf,
                                                       const ushort_t* __restrict__ Bh,
                                                       const float* __restrict__ b1,
                                                       ushort_t* __restrict__ h) {
  __shared__ ushort_t As[3][4096];
  __shared__ ushort_t Bs[3][8192];

  const int tid = threadIdx.x;
  const int id  = blockIdx.x;
  const int xcd = id & 7, local = id >> 3;
  const int rb  = (xcd << 4) + (local & 15);
  const int cb  = local >> 4;
  const int row0 = rb << 7, col0 = cb << 8;

  const int lane = tid & 63, wv = tid >> 6;
  const int m_base = (wv >> 2) << 6, n_base = (wv & 3) << 6;
  const int l15 = lane & 15, l4 = lane >> 4;

  const int arow = tid >> 2, acpos = tid & 3;
  const int acdata = acpos ^ ((arow >> 1) & 3);
  const ushort_t* aptr = Abf + (size_t)(row0 + arow) * K_PAD + acdata * 8;
  const ushort_t* bptr = Bh + (size_t)cb * NT * 8192 + tid * 8;

  int aoff[4], boff[4];
#pragma unroll
  for (int i = 0; i < 4; ++i) {
    const int r = m_base + i * 16 + l15;
    aoff[i] = r * 32 + (l4 ^ ((r >> 1) & 3)) * 8;
  }
#pragma unroll
  for (int j = 0; j < 4; ++j) {
    const int r = n_base + j * 16 + l15;
    boff[j] = r * 32 + (l4 ^ ((r >> 1) & 3)) * 8;
  }

  f32x4 acc[4][4];
#pragma unroll
  for (int i = 0; i < 4; ++i)
#pragma unroll
    for (int j = 0; j < 4; ++j) acc[i][j] = (f32x4){0.f, 0.f, 0.f, 0.f};

  auto prefetch = [&](int buf) {
    glds16(aptr,        &As[buf][tid * 8]);
    glds16(bptr,        &Bs[buf][tid * 8]);
    glds16(bptr + 4096, &Bs[buf][tid * 8 + 4096]);
    aptr += 32;
    bptr += 8192;
  };
  auto compute = [&](int buf) {
    bf16x8 ah[4], bh[4];
#pragma unroll
    for (int i = 0; i < 4; ++i) ah[i] = *(const bf16x8*)(&As[buf][aoff[i]]);
#pragma unroll
    for (int j = 0; j < 4; ++j) bh[j] = *(const bf16x8*)(&Bs[buf][boff[j]]);
#pragma unroll
    for (int i = 0; i < 4; ++i)
#pragma unroll
      for (int j = 0; j < 4; ++j)
        acc[i][j] = __builtin_amdgcn_mfma_f32_16x16x32_bf16(ah[i], bh[j], acc[i][j], 0, 0, 0);
  };

  prefetch(0);
  prefetch(1);
  asm volatile("s_waitcnt vmcnt(3)" ::: "memory");
  __builtin_amdgcn_s_barrier();
  __builtin_amdgcn_sched_barrier(0);

#define STEP(BUFC, BUFP) { prefetch(BUFP); compute(BUFC); \
    asm volatile("s_waitcnt vmcnt(3)" ::: "memory"); \
    __builtin_amdgcn_s_barrier(); \
    __builtin_amdgcn_sched_barrier(0); }
  for (int tt = 0; tt < 31; ++tt) {
    STEP(0, 2)
    STEP(1, 0)
    STEP(2, 1)
  }
#undef STEP
  compute(0);
  asm volatile("s_waitcnt vmcnt(0)" ::: "memory");
  __builtin_amdgcn_s_barrier();
  __builtin_amdgcn_sched_barrier(0);
  compute(1);

  float bb[4];
#pragma unroll
  for (int j = 0; j < 4; ++j) bb[j] = b1[col0 + n_base + j * 16 + l15];
#pragma unroll
  for (int i = 0; i < 4; ++i) {
    const int rbase = row0 + m_base + i * 16 + l4 * 4;
#pragma unroll
    for (int j = 0; j < 4; ++j) {
      const int c = col0 + n_base + j * 16 + l15;
#pragma unroll
      for (int q = 0; q < 4; ++q) {
        const float v = fmaxf(acc[i][j][q] + bb[j], 0.f);
        h[(size_t)(rbase + q) * HID + c] = f2bf(v);
      }
    }
  }
}

// ---------------- GEMM2: out = h @ W2 + b2 via bf16 MFMA ----------------
__global__ __launch_bounds__(256) void gemm2_kernel(const ushort_t* __restrict__ h,
                                                    const ushort_t* __restrict__ W2t,
                                                    const float* __restrict__ b2,
                                                    float* __restrict__ out) {
  const int tid = threadIdx.x;
  const int lane = tid & 63, wv = tid >> 6;
  const int rowt = wv & 1, colt = wv >> 1;
  const int l15 = lane & 15, l4 = lane >> 4;
  const int row0 = blockIdx.x * 32 + rowt * 16;
  const int col  = colt * 16 + l15;

  f32x4 acc = (f32x4){0.f, 0.f, 0.f, 0.f};
  const ushort_t* ha = h + (size_t)(row0 + l15) * HID + l4 * 8;
  const ushort_t* wb = W2t + (size_t)col * HID + l4 * 8;
#pragma unroll 8
  for (int k0 = 0; k0 < HID; k0 += 32) {
    const bf16x8 av = *(const bf16x8*)(ha + k0);
    const bf16x8 bv = *(const bf16x8*)(wb + k0);
    acc = __builtin_amdgcn_mfma_f32_16x16x32_bf16(av, bv, acc, 0, 0, 0);
  }
  if (col < OUT_DIM) {
    const float bias = b2[col];
#pragma unroll
    for (int q = 0; q < 4; ++q) {
      const int r = row0 + l4 * 4 + q;
      out[(size_t)r * OUT_DIM + col] = acc[q] + bias;
    }
  }
}

extern "C" void kernel_launch(void* const* d_in, const int* in_sizes, int n_in,
                              void* d_out, int out_size, void* d_ws, size_t ws_size,
                              hipStream_t stream) {
  (void)in_sizes; (void)n_in; (void)out_size;
  const float* x      = (const float*)d_in[0];
  const float* coords = (const float*)d_in[1];
  const float* genes  = (const float*)d_in[2];
  const float* W1     = (const float*)d_in[3];
  const float* b1     = (const float*)d_in[4];
  const float* W2     = (const float*)d_in[5];
  const float* b2     = (const float*)d_in[6];
  float* out = (float*)d_out;

  char* ws = (char*)d_ws;
  size_t off = 0;
  auto alloc = [&](size_t bytes) -> void* {
    void* p = ws + off;
    off = (off + bytes + 255) & ~(size_t)255;
    return p;
  };
  ushort_t* Abf    = (ushort_t*)alloc((size_t)N_CELLS * K_PAD * 2);   // 99.6 MB
  ushort_t* hbf    = (ushort_t*)alloc((size_t)N_CELLS * HID * 2);     // 33.5 MB
  ushort_t* Bh     = (ushort_t*)alloc((size_t)4 * NT * 8192 * 2);     // 6.2 MB
  ushort_t* W2t    = (ushort_t*)alloc((size_t)32 * HID * 2);          // 64 KB
  float*    GwsT   = (float*)alloc((size_t)64 * N_CELLS * 4);
  float*    VwsT   = (float*)alloc((size_t)64 * N_CELLS * 4);
  float*    lamT   = (float*)alloc((size_t)8 * N_CELLS * 4);
  int*      nidx   = (int*)alloc((size_t)N_CELLS * 8 * 4);
  double*   part   = (double*)alloc((size_t)128 * 32 * 8);
  float*    meanv  = (float*)alloc(G_GENES * 4);
  int*      binCnt = (int*)alloc((size_t)NBINS * 4);
  int*      binSt  = (int*)alloc((size_t)(NBINS + 1) * 4);
  int*      cursor = (int*)alloc((size_t)NBINS * 4);
  int*      binOf  = (int*)alloc((size_t)N_CELLS * 4);
  int*      binPts = (int*)alloc((size_t)N_CELLS * 4);
  float2*   sxy    = (float2*)alloc((size_t)N_CELLS * 8);
  if (off > ws_size) return;

  hipMemsetAsync(binCnt, 0, (size_t)NBINS * 4, stream);

  hipLaunchKernelGGL(fused_pre,   dim3(2624),  dim3(256), 0, stream,
                     x, W1, W2, genes, coords, Abf, Bh, W2t, part, binCnt, binOf);
  hipLaunchKernelGGL(scan_fin,    dim3(2),     dim3(256), 0, stream, binCnt, binSt, cursor, part, meanv);
  hipLaunchKernelGGL(bin_scatter, dim3(64),    dim3(256), 0, stream, coords, binOf, cursor, binPts, sxy);
  hipLaunchKernelGGL(knn_search,  dim3(256),   dim3(64),  0, stream, binSt, binPts, sxy, nidx);
  hipLaunchKernelGGL(gram_kernel, dim3(4096),  dim3(256), 0, stream, genes, meanv, nidx, GwsT);
  hipLaunchKernelGGL(jacobi_kernel, dim3(256), dim3(64),  0, stream, GwsT, VwsT, lamT);
  hipLaunchKernelGGL(recon_kernel,  dim3(4096), dim3(256), 0, stream, genes, meanv, nidx, VwsT, lamT, Abf);
  hipLaunchKernelGGL(gemm1_kernel,  dim3(512),  dim3(512), 0, stream, Abf, Bh, b1, hbf);
  hipLaunchKernelGGL(gemm2_kernel,  dim3(512),  dim3(256), 0, stream, hbf, W2t, b2, out);
}

// Round 15
// 252.362 us; speedup vs baseline: 1.0668x; 1.0577x over previous
//
#include <hip/hip_runtime.h>
#include <hip/hip_bf16.h>
#include <math.h>

#define N_CELLS 16384
#define G_GENES 32
#define IN_DIM  2000
#define HID     1024
#define OUT_DIM 30
#define K_TOT   3024      // IN_DIM + 1024
#define K_PAD   3040      // 95 * 32
#define NT      95
#define GRID_B  128
#define NBINS   (GRID_B * GRID_B)
#define SCELL   (100.0f / (float)GRID_B)
#define CSCALE  0.37796447300922722721f   // 1/sqrt(7)

typedef unsigned short ushort_t;
typedef __attribute__((ext_vector_type(8))) short bf16x8;
typedef __attribute__((ext_vector_type(4))) short bf16x4;
typedef __attribute__((ext_vector_type(4))) float f32x4;

__device__ __forceinline__ ushort_t f2bf(float v) {
  return __builtin_bit_cast(ushort_t, __float2bfloat16(v));
}

// global_load_lds: 16B per lane, LDS dest = wave-uniform base + lane*16
__device__ __forceinline__ void glds16(const void* g, void* l) {
  __builtin_amdgcn_global_load_lds(
      (const __attribute__((address_space(1))) unsigned int*)g,
      (__attribute__((address_space(3))) unsigned int*)l, 16, 0, 0);
}

// ============ fused pre-pass: packb | packw2 | convx | mean_part | bin_count ============
__global__ __launch_bounds__(256) void fused_pre(const float* __restrict__ x,
                                                 const float* __restrict__ W1,
                                                 const float* __restrict__ W2,
                                                 const float* __restrict__ genes,
                                                 const float* __restrict__ coords,
                                                 ushort_t* __restrict__ Abf,
                                                 ushort_t* __restrict__ Bh,
                                                 ushort_t* __restrict__ W2t,
                                                 double* __restrict__ part,
                                                 int* __restrict__ cnt,
                                                 int* __restrict__ binOf) {
  __shared__ float L[32][260];
  __shared__ double red[256];
  const int bid = blockIdx.x;
  const int tid = threadIdx.x;

  if (bid < 380) {
    // ---- packb: W1^T -> swizzled bf16 tiles [4 cb][95 t][256n x 32k] ----
    const int cb = bid / NT, t = bid % NT;
    const int k0 = t * 32, n0 = cb * 256;
    {
      const int kl = tid >> 3;
      const int nw = tid & 7;
#pragma unroll
      for (int u = 0; u < 8; ++u) {
        const int nl = (nw + u * 8) * 4;
        float4 v = make_float4(0.f, 0.f, 0.f, 0.f);
        if (k0 + kl < K_TOT) v = *(const float4*)(W1 + (size_t)(k0 + kl) * HID + n0 + nl);
        L[kl][nl + 0] = v.x; L[kl][nl + 1] = v.y; L[kl][nl + 2] = v.z; L[kl][nl + 3] = v.w;
      }
    }
    __syncthreads();
    const size_t tileBase = ((size_t)cb * NT + t) * 8192;
    const int n = tid;
#pragma unroll
    for (int q = 0; q < 4; ++q) {
      const int cdata = q ^ ((n >> 1) & 3);
      ushort_t hi[8];
#pragma unroll
      for (int e = 0; e < 8; ++e) {
        const int kl = cdata * 8 + e;
        const float v = (k0 + kl < K_TOT) ? L[kl][n] : 0.f;
        hi[e] = f2bf(v);
      }
      *(bf16x8*)(Bh + tileBase + ((size_t)n * 4 + q) * 8) = *(const bf16x8*)hi;
    }
  } else if (bid < 384) {
    // ---- packw2: W2 -> W2t bf16 [32][1024] (pad 30->32 with zeros) ----
    const int k = (bid - 380) * 256 + tid;
#pragma unroll
    for (int o = 0; o < 32; ++o) {
      const float v = (o < OUT_DIM) ? W2[k * OUT_DIM + o] : 0.f;
      W2t[o * HID + k] = f2bf(v);
    }
  } else if (bid < 2432) {
    // ---- convx: 8 rows per block ----
    const int rbase = (bid - 384) * 8;
#pragma unroll
    for (int rr = 0; rr < 8; ++rr) {
      const int row = rbase + rr;
      if (tid < 250) {
#pragma unroll
        for (int ph = 0; ph < 2; ++ph) {
          const int col = ph * 1000 + tid * 4;
          const float4 v = *(const float4*)(x + (size_t)row * IN_DIM + col);
          ushort_t o[4] = { f2bf(v.x), f2bf(v.y), f2bf(v.z), f2bf(v.w) };
          *(bf16x4*)(Abf + (size_t)row * K_PAD + col) = *(const bf16x4*)o;
        }
      } else if (tid < 252) {
        const bf16x8 z = (bf16x8){0, 0, 0, 0, 0, 0, 0, 0};
        *(bf16x8*)(Abf + (size_t)row * K_PAD + K_TOT + (tid - 250) * 8) = z;
      }
    }
  } else if (bid < 2560) {
    // ---- mean_part ----
    const int b = bid - 2432;
    const int g = tid & 31, cs = tid >> 5;
    double acc = 0.0;
#pragma unroll
    for (int it = 0; it < 16; ++it) {
      const int cell = b * 128 + cs + it * 8;
      acc += (double)genes[cell * G_GENES + g];
    }
    red[tid] = acc;
    __syncthreads();
    if (tid < 32) {
      double s = red[tid];
#pragma unroll
      for (int u = 1; u < 8; ++u) s += red[tid + u * 32];
      part[b * 32 + tid] = s;
    }
  } else {
    // ---- bin_count ----
    const int i = (bid - 2560) * 256 + tid;
    const float2 p = ((const float2*)coords)[i];
    const float inv_s = (float)GRID_B / 100.0f;
    const int bx = min(GRID_B - 1, max(0, (int)(p.x * inv_s)));
    const int by = min(GRID_B - 1, max(0, (int)(p.y * inv_s)));
    const int b = by * GRID_B + bx;
    binOf[i] = b;
    atomicAdd(&cnt[b], 1);
  }
}

// ============ block 0: bin prefix-scan | block 1: mean finalize ============
__global__ __launch_bounds__(256) void scan_fin(const int* __restrict__ cnt,
                                                int* __restrict__ binStart,
                                                int* __restrict__ cursor,
                                                const double* __restrict__ part,
                                                float* __restrict__ meanv) {
  const int tid = threadIdx.x;
  if (blockIdx.x == 0) {
    __shared__ int ps[256];
    int s = 0;
    for (int i = 0; i < 64; ++i) s += cnt[tid * 64 + i];
    ps[tid] = s;
    __syncthreads();
    for (int off = 1; off < 256; off <<= 1) {
      const int add = (tid >= off) ? ps[tid - off] : 0;
      __syncthreads();
      ps[tid] += add;
      __syncthreads();
    }
    int run = ps[tid] - s;
    for (int i = 0; i < 64; ++i) {
      const int b = tid * 64 + i;
      binStart[b] = run;
      cursor[b] = run;
      run += cnt[b];
    }
    if (tid == 255) binStart[NBINS] = run;
  } else {
    if (tid < 32) {
      double s = 0.0;
      for (int b = 0; b < 128; ++b) s += part[b * 32 + tid];
      meanv[tid] = (float)(s / (double)N_CELLS);
    }
  }
}

// ---------------- scatter: also build bin-sorted coords stream ----------------
__global__ __launch_bounds__(256) void bin_scatter(const float* __restrict__ coords,
                                                   const int* __restrict__ binOf,
                                                   int* __restrict__ cursor,
                                                   int* __restrict__ binPts,
                                                   float2* __restrict__ sxy) {
  const int i = blockIdx.x * 256 + threadIdx.x;
  const float2 p = ((const float2*)coords)[i];
  const int pos = atomicAdd(&cursor[binOf[i]], 1);
  binPts[pos] = i;
  sxy[pos] = p;
}

// ---------------- kNN in BIN-SORTED order; 256 blocks x 64 -> every CU ----------------
__global__ __launch_bounds__(64) void knn_search(const int* __restrict__ binStart,
                                                 const int* __restrict__ binPts,
                                                 const float2* __restrict__ sxy,
                                                 int* __restrict__ nidx) {
  const int rank = blockIdx.x * 64 + threadIdx.x;
  const int cell = binPts[rank];
  const float2 qv = sxy[rank];
  const float qx = qv.x, qy = qv.y;
  const float sqi = __fadd_rn(__fmul_rn(qx, qx), __fmul_rn(qy, qy));
  const float inv_s = (float)GRID_B / 100.0f;
  const int bx = min(GRID_B - 1, max(0, (int)(qx * inv_s)));
  const int by = min(GRID_B - 1, max(0, (int)(qy * inv_s)));

  unsigned long long kk[8];
#pragma unroll
  for (int i = 0; i < 8; ++i) kk[i] = ~0ull;

  auto scan_seg = [&](int s, int e) {
    for (int p = s; p < e; ++p) {
      const float2 pc = sxy[p];
      const int j = binPts[p];
      const float sqj = __fadd_rn(__fmul_rn(pc.x, pc.x), __fmul_rn(pc.y, pc.y));
      const float dot = __fmaf_rn(qy, pc.y, __fmul_rn(qx, pc.x));
      const float d2  = __fsub_rn(__fadd_rn(sqi, sqj), __fmul_rn(2.0f, dot));
      unsigned int sb = __float_as_uint(d2);
      sb = (sb & 0x80000000u) ? ~sb : (sb | 0x80000000u);
      unsigned long long key = ((unsigned long long)sb << 32) | (unsigned int)j;
      if (key < kk[7]) {
#pragma unroll
        for (int q2 = 0; q2 < 8; ++q2) {
          const bool lt = key < kk[q2];
          const unsigned long long tmp = kk[q2];
          kk[q2] = lt ? key : kk[q2];
          key = lt ? tmp : key;
        }
      }
    }
  };

  bool done = false;
  for (int r = 0; r < GRID_B; ++r) {
    if (!done) {
      if (r == 0) {
        const int b = by * GRID_B + bx;
        scan_seg(binStart[b], binStart[b + 1]);
      } else {
        const int xlo = max(0, bx - r), xhi = min(GRID_B - 1, bx + r);
        if (by - r >= 0) {
          const int b0 = (by - r) * GRID_B;
          scan_seg(binStart[b0 + xlo], binStart[b0 + xhi + 1]);
        }
        if (by + r < GRID_B) {
          const int b0 = (by + r) * GRID_B;
          scan_seg(binStart[b0 + xlo], binStart[b0 + xhi + 1]);
        }
        for (int dy = -r + 1; dy <= r - 1; ++dy) {
          const int yy = by + dy;
          if (yy < 0 || yy >= GRID_B) continue;
          if (bx - r >= 0) { const int b = yy * GRID_B + bx - r; scan_seg(binStart[b], binStart[b + 1]); }
          if (bx + r < GRID_B) { const int b = yy * GRID_B + bx + r; scan_seg(binStart[b], binStart[b + 1]); }
        }
      }
      if (kk[7] != ~0ull) {
        const unsigned int sb = (unsigned int)(kk[7] >> 32);
        const float wd2 = __uint_as_float((sb & 0x80000000u) ? (sb ^ 0x80000000u) : ~sb);
        const float bnd = (float)r * SCELL;
        if (wd2 < bnd * bnd * 0.998f - 0.05f) done = true;
      }
    }
    if (!__any(!done)) break;
  }
#pragma unroll
  for (int i = 0; i < 8; ++i) nidx[cell * 8 + i] = (int)(kk[i] & 0xFFFFFFFFu);
}

// ---------------- Gram -> transposed [64][N_CELLS]; float4 gather ----------------
__global__ __launch_bounds__(256) void gram_kernel(const float* __restrict__ genes,
                                                   const float* __restrict__ meanv,
                                                   const int* __restrict__ nidx,
                                                   float* __restrict__ GwsT) {
  const int wv = threadIdx.x >> 6, lane = threadIdx.x & 63;
  const int bidl = (blockIdx.x & 7) * 512 + (blockIdx.x >> 3);   // bijective 4096
  const int cell = bidl * 4 + wv;
  __shared__ float A[4][8][36];
  {
    const int n = lane >> 3;
    const int c = (lane & 7) << 2;
    const int src = nidx[cell * 8 + n];
    const float4 v = *(const float4*)(genes + (size_t)src * G_GENES + c);
    float o[4] = { (v.x - meanv[c + 0]) * CSCALE, (v.y - meanv[c + 1]) * CSCALE,
                   (v.z - meanv[c + 2]) * CSCALE, (v.w - meanv[c + 3]) * CSCALE };
    *(float4*)&A[wv][n][c] = *(const float4*)o;
  }
  __syncthreads();
  const int i = lane >> 3, j = lane & 7;
  float acc = 0.f;
#pragma unroll
  for (int g = 0; g < 32; ++g) acc = fmaf(A[wv][i][g], A[wv][j][g], acc);
  GwsT[(size_t)lane * N_CELLS + cell] = acc;
}

// ---------------- 8x8 Jacobi: lane=cell, coalesced I/O, fast t/c/s ----------------
__global__ __launch_bounds__(64) void jacobi_kernel(const float* __restrict__ GwsT,
                                                    float* __restrict__ VwsT,
                                                    float* __restrict__ lamT) {
  const int cell = blockIdx.x * 64 + threadIdx.x;
  float Gm[8][8], V[8][8];
#pragma unroll
  for (int e = 0; e < 64; ++e) Gm[e >> 3][e & 7] = GwsT[(size_t)e * N_CELLS + cell];
#pragma unroll
  for (int i = 0; i < 8; ++i)
#pragma unroll
    for (int j = 0; j < 8; ++j) V[i][j] = (i == j) ? 1.0f : 0.0f;

  for (int sweep = 0; sweep < 5; ++sweep) {
#pragma unroll
    for (int p = 0; p < 7; ++p) {
#pragma unroll
      for (int q = p + 1; q < 8; ++q) {
        const float apq = Gm[p][q];
        const float app = Gm[p][p], aqq = Gm[q][q];
        float t;
        if (apq != 0.0f) {
          const float tau = (aqq - app) * __builtin_amdgcn_rcpf(2.0f * apq);
          const float r = sqrtf(fmaf(tau, tau, 1.0f));
          t = copysignf(1.0f, tau) * __builtin_amdgcn_rcpf(fabsf(tau) + r);
        } else {
          t = 0.0f;
        }
        const float c = __builtin_amdgcn_rsqf(fmaf(t, t, 1.0f));
        const float s = t * c;
#pragma unroll
        for (int r2 = 0; r2 < 8; ++r2) {
          const float gp = Gm[p][r2], gq = Gm[q][r2];
          Gm[p][r2] = fmaf(c, gp, -s * gq);
          Gm[q][r2] = fmaf(s, gp,  c * gq);
        }
#pragma unroll
        for (int r2 = 0; r2 < 8; ++r2) {
          const float gp = Gm[r2][p], gq = Gm[r2][q];
          Gm[r2][p] = fmaf(c, gp, -s * gq);
          Gm[r2][q] = fmaf(s, gp,  c * gq);
        }
#pragma unroll
        for (int r2 = 0; r2 < 8; ++r2) {
          const float vp = V[r2][p], vq = V[r2][q];
          V[r2][p] = fmaf(c, vp, -s * vq);
          V[r2][q] = fmaf(s, vp,  c * vq);
        }
      }
    }
  }
#pragma unroll
  for (int e = 0; e < 64; ++e) VwsT[(size_t)e * N_CELLS + cell] = V[e >> 3][e & 7];
#pragma unroll
  for (int m = 0; m < 8; ++m) lamT[(size_t)m * N_CELLS + cell] = Gm[m][m];
}

// ---------------- covet (bf16) -> Abf cols 2000..3023; float4 gather ----------------
__global__ __launch_bounds__(256) void recon_kernel(const float* __restrict__ genes,
                                                    const float* __restrict__ meanv,
                                                    const int* __restrict__ nidx,
                                                    const float* __restrict__ VwsT,
                                                    const float* __restrict__ lamT,
                                                    ushort_t* __restrict__ Abf) {
  const int wv = threadIdx.x >> 6, lane = threadIdx.x & 63;
  const int cell = blockIdx.x * 4 + wv;
  __shared__ float A[4][8][36];
  __shared__ float Ws[4][8][33];
  __shared__ float Vs[4][64];
  __shared__ float lamS[4][8];
  {
    const int n = lane >> 3;
    const int c = (lane & 7) << 2;
    const int src = nidx[cell * 8 + n];
    const float4 v = *(const float4*)(genes + (size_t)src * G_GENES + c);
    float o[4] = { (v.x - meanv[c + 0]) * CSCALE, (v.y - meanv[c + 1]) * CSCALE,
                   (v.z - meanv[c + 2]) * CSCALE, (v.w - meanv[c + 3]) * CSCALE };
    *(float4*)&A[wv][n][c] = *(const float4*)o;
  }
  Vs[wv][lane] = VwsT[(size_t)lane * N_CELLS + cell];
  if (lane < 8) lamS[wv][lane] = lamT[(size_t)lane * N_CELLS + cell];
  __syncthreads();

  float maxl = 0.f;
#pragma unroll
  for (int m = 0; m < 8; ++m) maxl = fmaxf(maxl, lamS[wv][m]);
  const float thr = maxl * 1e-8f;

#pragma unroll
  for (int q = 0; q < 4; ++q) {
    const int e = lane + (q << 6);
    const int m = e >> 5, g = e & 31;
    float acc = 0.f;
#pragma unroll
    for (int i = 0; i < 8; ++i) acc = fmaf(Vs[wv][i * 8 + m], A[wv][i][g], acc);
    const float l = lamS[wv][m];
    const float scm = (l > thr) ? sqrtf(1.0f / sqrtf(l)) : 0.0f;
    Ws[wv][m][g] = acc * scm;
  }
  __syncthreads();
  ushort_t* dst = Abf + (size_t)cell * K_PAD + IN_DIM;
#pragma unroll
  for (int r = 0; r < 16; ++r) {
    const int o = (r << 6) + lane;
    const int g = o >> 5, hh = o & 31;
    float acc = 0.f;
#pragma unroll
    for (int m = 0; m < 8; ++m) acc = fmaf(Ws[wv][m][g], Ws[wv][m][hh], acc);
    dst[o] = f2bf(acc);
  }
}

// ---------------- GEMM1 + fused GEMM2 partials ----------------
// Main K-loop: round-8 proven structure, UNCHANGED (3-buf glds, vmcnt(3), raw barrier).
// Epilogue: h-tile -> LDS (bf16, identical rounding as before) -> mini-GEMM vs W2t
// -> deterministic per-cb partial buffer part4[cb][16384][32].
__global__ __launch_bounds__(512, 4) void gemm1_kernel(const ushort_t* __restrict__ Abf,
                                                       const ushort_t* __restrict__ Bh,
                                                       const float* __restrict__ b1,
                                                       const ushort_t* __restrict__ W2t,
                                                       float* __restrict__ part4) {
  __shared__ ushort_t smem[36864];   // 72 KB: As(3x4096) + Bs(3x8192); reused as Hs[128][264]
  ushort_t* As = smem;
  ushort_t* Bs = smem + 12288;

  const int tid = threadIdx.x;
  const int id  = blockIdx.x;
  const int xcd = id & 7, local = id >> 3;
  const int rb  = (xcd << 4) + (local & 15);
  const int cb  = local >> 4;
  const int row0 = rb << 7, col0 = cb << 8;

  const int lane = tid & 63, wv = tid >> 6;
  const int m_base = (wv >> 2) << 6, n_base = (wv & 3) << 6;
  const int l15 = lane & 15, l4 = lane >> 4;

  const int arow = tid >> 2, acpos = tid & 3;
  const int acdata = acpos ^ ((arow >> 1) & 3);
  const ushort_t* aptr = Abf + (size_t)(row0 + arow) * K_PAD + acdata * 8;
  const ushort_t* bptr = Bh + (size_t)cb * NT * 8192 + tid * 8;

  int aoff[4], boff[4];
#pragma unroll
  for (int i = 0; i < 4; ++i) {
    const int r = m_base + i * 16 + l15;
    aoff[i] = r * 32 + (l4 ^ ((r >> 1) & 3)) * 8;
  }
#pragma unroll
  for (int j = 0; j < 4; ++j) {
    const int r = n_base + j * 16 + l15;
    boff[j] = r * 32 + (l4 ^ ((r >> 1) & 3)) * 8;
  }

  f32x4 acc[4][4];
#pragma unroll
  for (int i = 0; i < 4; ++i)
#pragma unroll
    for (int j = 0; j < 4; ++j) acc[i][j] = (f32x4){0.f, 0.f, 0.f, 0.f};

  auto prefetch = [&](int buf) {
    glds16(aptr,        As + buf * 4096 + tid * 8);
    glds16(bptr,        Bs + buf * 8192 + tid * 8);
    glds16(bptr + 4096, Bs + buf * 8192 + tid * 8 + 4096);
    aptr += 32;
    bptr += 8192;
  };
  auto compute = [&](int buf) {
    bf16x8 ah[4], bh[4];
#pragma unroll
    for (int i = 0; i < 4; ++i) ah[i] = *(const bf16x8*)(As + buf * 4096 + aoff[i]);
#pragma unroll
    for (int j = 0; j < 4; ++j) bh[j] = *(const bf16x8*)(Bs + buf * 8192 + boff[j]);
#pragma unroll
    for (int i = 0; i < 4; ++i)
#pragma unroll
      for (int j = 0; j < 4; ++j)
        acc[i][j] = __builtin_amdgcn_mfma_f32_16x16x32_bf16(ah[i], bh[j], acc[i][j], 0, 0, 0);
  };

  prefetch(0);
  prefetch(1);
  asm volatile("s_waitcnt vmcnt(3)" ::: "memory");
  __builtin_amdgcn_s_barrier();
  __builtin_amdgcn_sched_barrier(0);

#define STEP(BUFC, BUFP) { prefetch(BUFP); compute(BUFC); \
    asm volatile("s_waitcnt vmcnt(3)" ::: "memory"); \
    __builtin_amdgcn_s_barrier(); \
    __builtin_amdgcn_sched_barrier(0); }
  for (int tt = 0; tt < 31; ++tt) {
    STEP(0, 2)
    STEP(1, 0)
    STEP(2, 1)
  }
#undef STEP
  compute(0);
  asm volatile("s_waitcnt vmcnt(0)" ::: "memory");
  __builtin_amdgcn_s_barrier();
  __builtin_amdgcn_sched_barrier(0);
  compute(1);

  // ---- epilogue: bias+relu+bf16 (identical rounding), stash h-tile in LDS ----
  float bb[4];
#pragma unroll
  for (int j = 0; j < 4; ++j) bb[j] = b1[col0 + n_base + j * 16 + l15];

  __syncthreads();                    // all waves done with As/Bs reads
  ushort_t* Hs = smem;                // [128][264] bf16, stride 264 (2-way banks max)
#pragma unroll
  for (int i = 0; i < 4; ++i) {
    const int rl = m_base + i * 16 + l4 * 4;
#pragma unroll
    for (int j = 0; j < 4; ++j) {
      const int cl = n_base + j * 16 + l15;
#pragma unroll
      for (int q = 0; q < 4; ++q) {
        const float v = fmaxf(acc[i][j][q] + bb[j], 0.f);
        Hs[(rl + q) * 264 + cl] = f2bf(v);
      }
    }
  }
  __syncthreads();

  // ---- mini-GEMM: wave wv owns rows wv*16..+15; K=256 (this block's h cols);
  //      out cols 0..31 (two 16x16 tiles); B-frags straight from L2-hot W2t ----
  f32x4 o0 = (f32x4){0.f, 0.f, 0.f, 0.f};
  f32x4 o1 = (f32x4){0.f, 0.f, 0.f, 0.f};
  const ushort_t* w2b = W2t + col0 + l4 * 8;
#pragma unroll
  for (int kt = 0; kt < 8; ++kt) {
    const bf16x8 af = *(const bf16x8*)(Hs + (wv * 16 + l15) * 264 + kt * 32 + l4 * 8);
    const bf16x8 b0 = *(const bf16x8*)(w2b + (size_t)l15 * HID + kt * 32);
    const bf16x8 b1f = *(const bf16x8*)(w2b + (size_t)(16 + l15) * HID + kt * 32);
    o0 = __builtin_amdgcn_mfma_f32_16x16x32_bf16(af, b0, o0, 0, 0, 0);
    o1 = __builtin_amdgcn_mfma_f32_16x16x32_bf16(af, b1f, o1, 0, 0, 0);
  }
  // C-layout: col=lane&15, row=(lane>>4)*4+q
  float* pdst = part4 + ((size_t)cb * N_CELLS + row0 + wv * 16 + l4 * 4) * 32 + l15;
#pragma unroll
  for (int q = 0; q < 4; ++q) {
    pdst[q * 32]      = o0[q];
    pdst[q * 32 + 16] = o1[q];
  }
}

// ---------------- reduce: out = sum_cb part4[cb] + b2 (fixed order: deterministic) ----------------
__global__ __launch_bounds__(256) void reduce_out(const float* __restrict__ part4,
                                                  const float* __restrict__ b2,
                                                  float* __restrict__ out) {
  const int t = blockIdx.x * 256 + threadIdx.x;   // over 16384*32
  const int n = t >> 5, o = t & 31;
  if (o >= OUT_DIM) return;
  const size_t str = (size_t)N_CELLS * 32;
  const float s = ((part4[t] + part4[t + str]) + part4[t + 2 * str]) + part4[t + 3 * str];
  out[(size_t)n * OUT_DIM + o] = s + b2[o];
}

extern "C" void kernel_launch(void* const* d_in, const int* in_sizes, int n_in,
                              void* d_out, int out_size, void* d_ws, size_t ws_size,
                              hipStream_t stream) {
  (void)in_sizes; (void)n_in; (void)out_size;
  const float* x      = (const float*)d_in[0];
  const float* coords = (const float*)d_in[1];
  const float* genes  = (const float*)d_in[2];
  const float* W1     = (const float*)d_in[3];
  const float* b1     = (const float*)d_in[4];
  const float* W2     = (const float*)d_in[5];
  const float* b2     = (const float*)d_in[6];
  float* out = (float*)d_out;

  char* ws = (char*)d_ws;
  size_t off = 0;
  auto alloc = [&](size_t bytes) -> void* {
    void* p = ws + off;
    off = (off + bytes + 255) & ~(size_t)255;
    return p;
  };
  ushort_t* Abf    = (ushort_t*)alloc((size_t)N_CELLS * K_PAD * 2);   // 99.6 MB
  float*    part4  = (float*)alloc((size_t)4 * N_CELLS * 32 * 4);     // 8.4 MB
  ushort_t* Bh     = (ushort_t*)alloc((size_t)4 * NT * 8192 * 2);     // 6.2 MB
  ushort_t* W2t    = (ushort_t*)alloc((size_t)32 * HID * 2);          // 64 KB
  float*    GwsT   = (float*)alloc((size_t)64 * N_CELLS * 4);
  float*    VwsT   = (float*)alloc((size_t)64 * N_CELLS * 4);
  float*    lamT   = (float*)alloc((size_t)8 * N_CELLS * 4);
  int*      nidx   = (int*)alloc((size_t)N_CELLS * 8 * 4);
  double*   part   = (double*)alloc((size_t)128 * 32 * 8);
  float*    meanv  = (float*)alloc(G_GENES * 4);
  int*      binCnt = (int*)alloc((size_t)NBINS * 4);
  int*      binSt  = (int*)alloc((size_t)(NBINS + 1) * 4);
  int*      cursor = (int*)alloc((size_t)NBINS * 4);
  int*      binOf  = (int*)alloc((size_t)N_CELLS * 4);
  int*      binPts = (int*)alloc((size_t)N_CELLS * 4);
  float2*   sxy    = (float2*)alloc((size_t)N_CELLS * 8);
  if (off > ws_size) return;

  hipMemsetAsync(binCnt, 0, (size_t)NBINS * 4, stream);

  hipLaunchKernelGGL(fused_pre,   dim3(2624),  dim3(256), 0, stream,
                     x, W1, W2, genes, coords, Abf, Bh, W2t, part, binCnt, binOf);
  hipLaunchKernelGGL(scan_fin,    dim3(2),     dim3(256), 0, stream, binCnt, binSt, cursor, part, meanv);
  hipLaunchKernelGGL(bin_scatter, dim3(64),    dim3(256), 0, stream, coords, binOf, cursor, binPts, sxy);
  hipLaunchKernelGGL(knn_search,  dim3(256),   dim3(64),  0, stream, binSt, binPts, sxy, nidx);
  hipLaunchKernelGGL(gram_kernel, dim3(4096),  dim3(256), 0, stream, genes, meanv, nidx, GwsT);
  hipLaunchKernelGGL(jacobi_kernel, dim3(256), dim3(64),  0, stream, GwsT, VwsT, lamT);
  hipLaunchKernelGGL(recon_kernel,  dim3(4096), dim3(256), 0, stream, genes, meanv, nidx, VwsT, lamT, Abf);
  hipLaunchKernelGGL(gemm1_kernel,  dim3(512),  dim3(512), 0, stream, Abf, Bh, b1, W2t, part4);
  hipLaunchKernelGGL(reduce_out,    dim3(2048), dim3(256), 0, stream, part4, b2, out);
}